// Round 1
// baseline (92.475 us; speedup 1.0000x reference)
//
#include <hip/hip_runtime.h>
#include <math.h>

#define HW     262144   // 512*512
#define WIDTH  512
#define BB     4
#define NN     32
#define KK     256
#define PP     8192
#define EPSF   1e-4f
#define ONE_M_EPS (1.0f - 1e-4f)
#define NEG_LOG_EPS 9.2103403719f    // -ln(1e-4)
#define NEG_LOG_1ME 1.00005003e-4f   // -ln(1-1e-4)

// ---- workspace layout (floats) ----
#define WS_CLS  0        // [2 tensors][256 blocks][3 sums] = 1536
#define WS_WH   1536     // [256 blocks][2 sums]            = 512
#define WS_TAN  2048     // [32 blocks]                     = 32
#define WS_VAR  2080     // [4*32]                          = 128
#define WS_INST 2208     // [64 chunks][384 rows]           = 24576
// total = 26784 floats = 107,136 bytes

__device__ __forceinline__ float ftanh(float x) {
    // tanh(x) = 1 - 2/(exp(2x)+1); saturates correctly at +-inf
    float e = __expf(2.0f * x);
    return 1.0f - 2.0f / (e + 1.0f);
}

__device__ __forceinline__ float wave_reduce(float v) {
    #pragma unroll
    for (int off = 1; off < 64; off <<= 1) v += __shfl_xor(v, off, 64);
    return v;
}

// block reduce; result valid on thread 0 only. sbuf >= blockDim/64 floats.
__device__ __forceinline__ float block_reduce(float v, float* sbuf) {
    v = wave_reduce(v);
    int lane = threadIdx.x & 63, wid = threadIdx.x >> 6;
    __syncthreads();                 // protect sbuf across repeated calls
    if (lane == 0) sbuf[wid] = v;
    __syncthreads();
    float r = 0.f;
    if (threadIdx.x == 0) {
        int nw = blockDim.x >> 6;
        for (int i = 0; i < nw; ++i) r += sbuf[i];
    }
    return r;
}

// ---- cls / kp focal partials: grid (256, 2), block 256 ----
__global__ void __launch_bounds__(256)
k_focal(const float* __restrict__ cls_out, const float* __restrict__ cls_mask,
        const float* __restrict__ kp_out,  const float* __restrict__ kp_mask,
        float* __restrict__ ws) {
    __shared__ float sbuf[4];
    int t = blockIdx.y;
    const float4* po = (const float4*)(t == 0 ? cls_out : kp_out);
    const float4* pm = (const float4*)(t == 0 ? cls_mask : kp_mask);
    const int nvec = (BB * HW) / 4;   // 262144
    float s_pos = 0.f, s_neg = 0.f, cnt = 0.f;
    for (int i = blockIdx.x * blockDim.x + threadIdx.x; i < nvec;
         i += gridDim.x * blockDim.x) {
        float4 xo = po[i], xm = pm[i];
        #pragma unroll
        for (int j = 0; j < 4; ++j) {
            float x = (&xo.x)[j], gt = (&xm.x)[j];
            float p = 1.0f / (1.0f + __expf(-x));     // sigmoid
            p = fminf(fmaxf(p, EPSF), ONE_M_EPS);     // _sig clip (focal clip idempotent)
            float omp = 1.0f - p;
            if (gt == 1.0f) {
                cnt  += 1.0f;
                s_pos += __logf(p) * omp * omp;
            } else {
                float og = 1.0f - gt;
                float negw = og * og; negw *= negw;   // (1-gt)^4
                s_neg += __logf(omp) * p * p * negw;
            }
        }
    }
    float r0 = block_reduce(s_pos, sbuf);
    float r1 = block_reduce(s_neg, sbuf);
    float r2 = block_reduce(cnt, sbuf);
    if (threadIdx.x == 0) {
        float* dst = ws + WS_CLS + (t * gridDim.x + blockIdx.x) * 3;
        dst[0] = r0; dst[1] = r1; dst[2] = r2;
    }
}

// ---- wh smooth-L1 partials: grid 256, block 256 ----
__global__ void __launch_bounds__(256)
k_wh(const float* __restrict__ o, const float* __restrict__ tg,
     const float* __restrict__ m, float* __restrict__ ws) {
    __shared__ float sbuf[4];
    const int nvec = (BB * 2 * HW) / 4;  // 524288
    const float4* po  = (const float4*)o;
    const float4* pt  = (const float4*)tg;
    const float4* pmk = (const float4*)m;
    float sl = 0.f, ms = 0.f;
    for (int i = blockIdx.x * blockDim.x + threadIdx.x; i < nvec;
         i += gridDim.x * blockDim.x) {
        float4 a = po[i], b = pt[i], c = pmk[i];
        #pragma unroll
        for (int j = 0; j < 4; ++j) {
            float mm = (&c.x)[j];
            float d  = (&a.x)[j] * mm - (&b.x)[j] * mm;
            float ad = fabsf(d);
            sl += (ad < 1.0f) ? 0.5f * d * d : (ad - 0.5f);
            ms += mm;
        }
    }
    float r0 = block_reduce(sl, sbuf);
    float r1 = block_reduce(ms, sbuf);
    if (threadIdx.x == 0) {
        ws[WS_WH + blockIdx.x * 2 + 0] = r0;
        ws[WS_WH + blockIdx.x * 2 + 1] = r1;
    }
}

// ---- tangent loss partials: grid 32 (b*8+seg), block 256 ----
__global__ void __launch_bounds__(256)
k_tan(const float* __restrict__ tan_out, const float* __restrict__ normals,
      const int* __restrict__ pts, float* __restrict__ ws) {
    __shared__ float sbuf[4];
    int b = blockIdx.x >> 3, seg = blockIdx.x & 7;
    float s = 0.f;
    for (int p = seg * 1024 + threadIdx.x; p < seg * 1024 + 1024; p += blockDim.x) {
        int base = (b * PP + p) * 2;
        int py = pts[base], px = pts[base + 1];
        int pix = py * WIDTH + px;
        float t0 = tan_out[b * 2 * HW + pix];
        float t1 = tan_out[b * 2 * HW + HW + pix];
        float inv = 1.0f / fmaxf(sqrtf(t0 * t0 + t1 * t1), EPSF);
        float n0 = normals[base], n1 = normals[base + 1];
        s += 1.0f - (n0 * t0 + n1 * t1) * inv;
    }
    float r = block_reduce(s, sbuf);
    if (threadIdx.x == 0) ws[WS_TAN + blockIdx.x] = r;
}

// ---- AE var loss partials: grid (32, 4) = (n, b), block 256 (= K) ----
__global__ void __launch_bounds__(256)
k_var(const float* __restrict__ ae, const int* __restrict__ centers,
      const int* __restrict__ kps, float* __restrict__ ws) {
    __shared__ float sbuf[4];
    __shared__ float cy[NN], cx[NN];
    int n = blockIdx.x, b = blockIdx.y;
    if (threadIdx.x < NN) {
        int cb = (b * NN + threadIdx.x) * 2;
        cy[threadIdx.x] = centers[cb]     * (1.0f / 512.0f);  // xym[0] = y/H
        cx[threadIdx.x] = centers[cb + 1] * (1.0f / 512.0f);  // xym[1] = x/W
    }
    __syncthreads();
    int k = threadIdx.x;
    int kb = ((b * NN + n) * KK + k) * 2;
    int ky = kps[kb], kx = kps[kb + 1];
    int pix = ky * WIDTH + kx;
    const float* aeb = ae + b * 4 * HW;
    float se0 = ftanh(aeb[pix])           + ky * (1.0f / 512.0f);
    float se1 = ftanh(aeb[HW + pix])      + kx * (1.0f / 512.0f);
    float sg0 = __expf(aeb[2 * HW + pix]);
    float sg1 = __expf(aeb[3 * HW + pix]);
    float own = 0.f, mx = -1e30f;
    #pragma unroll
    for (int m = 0; m < NN; ++m) {
        float d0 = se0 - cy[m], d1 = se1 - cx[m];
        float dist = __expf(-(d0 * d0 * sg0 + d1 * d1 * sg1));
        mx = fmaxf(mx, dist);
        if (m == n) own = dist;
    }
    float r = block_reduce(fabsf(own - mx), sbuf);
    if (threadIdx.x == 0) ws[WS_VAR + b * NN + n] = r;
}

// ---- AE instance focal partials (the heavy one) ----
// grid (64 chunks, 4 instance-groups, 4 batches), block 256.
// Each thread: 4 float4 pixel-groups x 8 instances; reads masks once, ae 4x.
__global__ void __launch_bounds__(256)
k_inst(const float* __restrict__ ae, const float* __restrict__ masks,
       const int* __restrict__ centers, float* __restrict__ ws) {
    __shared__ float cy[8], cx[8];
    __shared__ float sred[4][24];
    int chunk = blockIdx.x;   // 0..63
    int g     = blockIdx.y;   // 0..3
    int b     = blockIdx.z;   // 0..3
    int tid   = threadIdx.x;
    if (tid < 8) {
        int cb = (b * NN + g * 8 + tid) * 2;
        cy[tid] = centers[cb]     * (1.0f / 512.0f);
        cx[tid] = centers[cb + 1] * (1.0f / 512.0f);
    }
    __syncthreads();
    float a_pos[8], a_neg[8], a_cnt[8];
    #pragma unroll
    for (int i = 0; i < 8; ++i) { a_pos[i] = 0.f; a_neg[i] = 0.f; a_cnt[i] = 0.f; }
    const float4* aeb = (const float4*)(ae + (size_t)b * 4 * HW);
    const float4* mb  = (const float4*)(masks + (size_t)b * NN * HW);
    for (int p = 0; p < 4; ++p) {
        int v = chunk * 256 + tid + p * 16384;   // float4 index, 0..65535
        float4 a0 = aeb[v];
        float4 a1 = aeb[65536 + v];
        float4 a2 = aeb[2 * 65536 + v];
        float4 a3 = aeb[3 * 65536 + v];
        int pix0 = v * 4;
        float fy  = (float)(pix0 >> 9)  * (1.0f / 512.0f);
        float fx0 = (float)(pix0 & 511) * (1.0f / 512.0f);
        float se0[4], se1[4], sg0[4], sg1[4];
        #pragma unroll
        for (int j = 0; j < 4; ++j) {
            se0[j] = ftanh((&a0.x)[j]) + fy;
            se1[j] = ftanh((&a1.x)[j]) + fx0 + (float)j * (1.0f / 512.0f);
            sg0[j] = __expf((&a2.x)[j]);
            sg1[j] = __expf((&a3.x)[j]);
        }
        #pragma unroll
        for (int nl = 0; nl < 8; ++nl) {
            float4 mk = mb[(g * 8 + nl) * 65536 + v];
            float ccy = cy[nl], ccx = cx[nl];
            #pragma unroll
            for (int j = 0; j < 4; ++j) {
                float dy = se0[j] - ccy, dx = se1[j] - ccx;
                float s = dy * dy * sg0[j] + dx * dx * sg1[j];
                float e = __expf(-s);
                float pc = fminf(fmaxf(e, EPSF), ONE_M_EPS);
                // log(clip(exp(-s))) == -clamp(s, -ln(1-eps), -ln(eps))
                float lp = -fminf(fmaxf(s, NEG_LOG_1ME), NEG_LOG_EPS);
                float omp = 1.0f - pc;
                if ((&mk.x)[j] == 1.0f) {        // masks are exactly 0/1
                    a_cnt[nl] += 1.0f;
                    a_pos[nl] += lp * omp * omp;
                } else {
                    a_neg[nl] += __logf(omp) * pc * pc;  // neg_w == 1
                }
            }
        }
    }
    int lane = tid & 63, wid = tid >> 6;
    #pragma unroll
    for (int nl = 0; nl < 8; ++nl) {
        float v0 = wave_reduce(a_pos[nl]);
        float v1 = wave_reduce(a_neg[nl]);
        float v2 = wave_reduce(a_cnt[nl]);
        if (lane == 0) {
            sred[wid][nl * 3 + 0] = v0;
            sred[wid][nl * 3 + 1] = v1;
            sred[wid][nl * 3 + 2] = v2;
        }
    }
    __syncthreads();
    if (tid < 24) {
        float s = sred[0][tid] + sred[1][tid] + sred[2][tid] + sred[3][tid];
        int nl = tid / 3, si = tid - nl * 3;
        int row = (b * NN + g * 8 + nl) * 3 + si;
        ws[WS_INST + chunk * 384 + row] = s;   // [chunk][row] for coalesced finalize
    }
}

// ---- finalize: 1 block, 256 threads ----
__global__ void __launch_bounds__(256)
k_final(const float* __restrict__ ws, float* __restrict__ out) {
    __shared__ float sh[384];
    __shared__ float sbuf[4];
    int tid = threadIdx.x;
    {   // sum instance partials over 64 chunks (coalesced across rows)
        float acc0 = 0.f, acc1 = 0.f;
        for (int c = 0; c < 64; ++c) {
            acc0 += ws[WS_INST + c * 384 + tid];
            if (tid < 128) acc1 += ws[WS_INST + c * 384 + 256 + tid];
        }
        sh[tid] = acc0;
        if (tid < 128) sh[256 + tid] = acc1;
    }
    __syncthreads();
    float ae_v = 0.f;
    if (tid < 128) {   // tid == b*32+n
        float pos = sh[tid * 3 + 0], neg = sh[tid * 3 + 1], cnt = sh[tid * 3 + 2];
        float il = (cnt > 0.f) ? (-(pos + neg) / fmaxf(cnt, 1.0f)) : (-neg);
        ae_v = il + ws[WS_VAR + tid];
    }
    float ae_sum = block_reduce(ae_v, sbuf);

    float c0 = ws[WS_CLS + tid * 3 + 0];
    float c1 = ws[WS_CLS + tid * 3 + 1];
    float c2 = ws[WS_CLS + tid * 3 + 2];
    float cls_pos = block_reduce(c0, sbuf);
    float cls_neg = block_reduce(c1, sbuf);
    float cls_cnt = block_reduce(c2, sbuf);

    float k0 = ws[WS_CLS + 768 + tid * 3 + 0];
    float k1 = ws[WS_CLS + 768 + tid * 3 + 1];
    float k2 = ws[WS_CLS + 768 + tid * 3 + 2];
    float kp_pos = block_reduce(k0, sbuf);
    float kp_neg = block_reduce(k1, sbuf);
    float kp_cnt = block_reduce(k2, sbuf);

    float w0 = ws[WS_WH + tid * 2 + 0];
    float w1 = ws[WS_WH + tid * 2 + 1];
    float wh_sl = block_reduce(w0, sbuf);
    float wh_ms = block_reduce(w1, sbuf);

    float tn = (tid < 32) ? ws[WS_TAN + tid] : 0.f;
    float tan_sum = block_reduce(tn, sbuf);

    if (tid == 0) {
        float l_cls = (cls_cnt > 0.f) ? (-(cls_pos + cls_neg) / fmaxf(cls_cnt, 1.f)) : (-cls_neg);
        float l_kp  = (kp_cnt  > 0.f) ? (-(kp_pos  + kp_neg)  / fmaxf(kp_cnt,  1.f)) : (-kp_neg);
        float l_wh  = 0.1f * wh_sl / (wh_ms + 1e-4f);
        float l_ae  = ae_sum / (float)(NN * BB);
        float l_tan = tan_sum / (float)(PP * BB);
        out[0] = l_cls + l_wh + l_kp + l_ae + l_tan;
    }
}

extern "C" void kernel_launch(void* const* d_in, const int* in_sizes, int n_in,
                              void* d_out, int out_size, void* d_ws, size_t ws_size,
                              hipStream_t stream) {
    const float* cls_out     = (const float*)d_in[0];
    const float* wh_out      = (const float*)d_in[1];
    const float* kp_out      = (const float*)d_in[2];
    const float* ae_out      = (const float*)d_in[3];
    const float* tan_out     = (const float*)d_in[4];
    const float* cls_mask    = (const float*)d_in[5];
    const float* wh_target   = (const float*)d_in[6];
    const float* wh_mask     = (const float*)d_in[7];
    const float* kp_mask     = (const float*)d_in[8];
    const float* ae_masks    = (const float*)d_in[9];
    const float* tan_normals = (const float*)d_in[10];
    // d_in[11] = xym: analytic (y/512, x/512), not needed
    const int* centers    = (const int*)d_in[12];
    const int* kps        = (const int*)d_in[13];
    const int* tan_points = (const int*)d_in[14];
    float* ws  = (float*)d_ws;
    float* out = (float*)d_out;

    k_focal<<<dim3(256, 2), 256, 0, stream>>>(cls_out, cls_mask, kp_out, kp_mask, ws);
    k_wh   <<<256, 256, 0, stream>>>(wh_out, wh_target, wh_mask, ws);
    k_tan  <<<32, 256, 0, stream>>>(tan_out, tan_normals, tan_points, ws);
    k_var  <<<dim3(32, 4), 256, 0, stream>>>(ae_out, centers, kps, ws);
    k_inst <<<dim3(64, 4, 4), 256, 0, stream>>>(ae_out, ae_masks, centers, ws);
    k_final<<<1, 256, 0, stream>>>(ws, out);
}

// Round 2
// 57.882 us; speedup vs baseline: 1.5976x; 1.5976x over previous
//
#include <hip/hip_runtime.h>
#include <math.h>

#define HW     262144   // 512*512
#define WIDTH  512
#define BB     4
#define NN     32
#define KK     256
#define PP     8192
#define EPSF   1e-4f
#define ONE_M_EPS (1.0f - 1e-4f)
#define NEG_LOG_EPS 9.2103403719f    // -ln(1e-4)
#define NEG_LOG_1ME 1.00005003e-4f   // -ln(1-1e-4)

// ---- mega-kernel block partition (inst first: longest blocks dispatch first) ----
#define NBLK_INST  512   // 64 chunks x 2 groups x 4 batches
#define NBLK_FOCAL 128   // 2 tensors x 64
#define NBLK_WH    64
#define NBLK_TAN   32
#define NBLK_VAR   128   // 32 n x 4 b
#define NBLK_TOTAL (NBLK_INST + NBLK_FOCAL + NBLK_WH + NBLK_TAN + NBLK_VAR)  // 864

// ---- workspace layout (floats) ----
#define WS_INST  0       // [64 chunks][256]  (b*64 + g*32 + nl*2 + {sum,cnt})
#define WS_FOCAL 16384   // [2][64][2]
#define WS_WH    16640   // [64][2]
#define WS_TAN   16768   // [32]
#define WS_VAR   16800   // [128]
// total 16928 floats = 67,712 bytes

__device__ __forceinline__ float ftanh(float x) {
    float e = __expf(2.0f * x);
    return 1.0f - 2.0f / (e + 1.0f);
}

__device__ __forceinline__ float wave_reduce(float v) {
    #pragma unroll
    for (int off = 1; off < 64; off <<= 1) v += __shfl_xor(v, off, 64);
    return v;
}

__device__ __forceinline__ float block_reduce(float v, float* sbuf) {
    v = wave_reduce(v);
    int lane = threadIdx.x & 63, wid = threadIdx.x >> 6;
    __syncthreads();
    if (lane == 0) sbuf[wid] = v;
    __syncthreads();
    float r = 0.f;
    if (threadIdx.x == 0) {
        for (int i = 0; i < 4; ++i) r += sbuf[i];
    }
    return r;
}

// ---- AE instance focal: 16 instances/block, branchless ----
__device__ __forceinline__ void inst_part(int idx, const float* __restrict__ ae,
                                          const float* __restrict__ masks,
                                          const int* __restrict__ centers,
                                          float* __restrict__ ws, float* smem) {
    int chunk = idx & 63, g = (idx >> 6) & 1, b = idx >> 7;
    int tid = threadIdx.x;
    float* cy   = smem;        // [16]
    float* cx   = smem + 16;   // [16]
    float* sred = smem + 32;   // [4][32]
    if (tid < 16) {
        int cb = (b * NN + g * 16 + tid) * 2;
        cy[tid] = centers[cb]     * (1.0f / 512.0f);
        cx[tid] = centers[cb + 1] * (1.0f / 512.0f);
    }
    __syncthreads();
    float a_sum[16], a_cnt[16];
    #pragma unroll
    for (int i = 0; i < 16; ++i) { a_sum[i] = 0.f; a_cnt[i] = 0.f; }
    const float4* aeb = (const float4*)(ae + (size_t)b * 4 * HW);
    const float4* mb  = (const float4*)(masks + ((size_t)b * NN + g * 16) * HW);
    for (int p = 0; p < 4; ++p) {
        int v = chunk * 256 + tid + p * 16384;   // float4 index 0..65535
        float4 a0 = aeb[v];
        float4 a1 = aeb[65536 + v];
        float4 a2 = aeb[131072 + v];
        float4 a3 = aeb[196608 + v];
        int pix0 = v * 4;
        float fy  = (float)(pix0 >> 9)  * (1.0f / 512.0f);
        float fx0 = (float)(pix0 & 511) * (1.0f / 512.0f);
        float se0[4], se1[4], sg0[4], sg1[4];
        #pragma unroll
        for (int j = 0; j < 4; ++j) {
            se0[j] = ftanh((&a0.x)[j]) + fy;
            se1[j] = ftanh((&a1.x)[j]) + fx0 + (float)j * (1.0f / 512.0f);
            sg0[j] = __expf((&a2.x)[j]);
            sg1[j] = __expf((&a3.x)[j]);
        }
        #pragma unroll
        for (int nl = 0; nl < 16; ++nl) {
            float4 mk = mb[(size_t)nl * 65536 + v];
            float ccy = cy[nl], ccx = cx[nl];
            #pragma unroll
            for (int j = 0; j < 4; ++j) {
                float m  = (&mk.x)[j];                 // exactly 0.0 or 1.0
                float dy = se0[j] - ccy, dx = se1[j] - ccx;
                float s  = fmaf(dx * dx, sg1[j], dy * dy * sg0[j]);
                float e  = __expf(-s);
                float pc = fminf(fmaxf(e, EPSF), ONE_M_EPS);
                float omp = 1.0f - pc;
                float lp  = -fminf(fmaxf(s, NEG_LOG_1ME), NEG_LOG_EPS); // log(clip(exp(-s)))
                float pos_t = lp * omp * omp;
                float neg_t = __logf(omp) * pc * pc;   // neg_w == 1 (binary masks)
                a_sum[nl] += (m != 0.f) ? pos_t : neg_t;
                a_cnt[nl] += m;
            }
        }
    }
    int lane = tid & 63, wid = tid >> 6;
    #pragma unroll
    for (int nl = 0; nl < 16; ++nl) {
        float v0 = wave_reduce(a_sum[nl]);
        float v1 = wave_reduce(a_cnt[nl]);
        if (lane == 0) { sred[wid * 32 + nl * 2] = v0; sred[wid * 32 + nl * 2 + 1] = v1; }
    }
    __syncthreads();
    if (tid < 32) {
        float s = sred[tid] + sred[32 + tid] + sred[64 + tid] + sred[96 + tid];
        ws[WS_INST + chunk * 256 + b * 64 + g * 32 + tid] = s;
    }
}

// ---- cls/kp focal: idx = t*64 + blk ----
__device__ __forceinline__ void focal_part(int idx, const float* __restrict__ cls_out,
                                           const float* __restrict__ cls_mask,
                                           const float* __restrict__ kp_out,
                                           const float* __restrict__ kp_mask,
                                           float* __restrict__ ws, float* sbuf) {
    int t = idx >> 6, blk = idx & 63;
    const float4* po = (const float4*)(t == 0 ? cls_out : kp_out);
    const float4* pm = (const float4*)(t == 0 ? cls_mask : kp_mask);
    float sum = 0.f, cnt = 0.f;
    #pragma unroll 4
    for (int it = 0; it < 16; ++it) {
        int i = blk * 256 + threadIdx.x + it * 16384;
        float4 xo = po[i], xm = pm[i];
        #pragma unroll
        for (int j = 0; j < 4; ++j) {
            float x = (&xo.x)[j], gt = (&xm.x)[j];
            float p = 1.0f / (1.0f + __expf(-x));
            p = fminf(fmaxf(p, EPSF), ONE_M_EPS);
            float omp = 1.0f - p;
            float pos_t = __logf(p) * omp * omp;
            float og = 1.0f - gt;
            float negw = og * og; negw *= negw;
            float neg_t = __logf(omp) * p * p * negw;
            bool ispos = (gt == 1.0f);
            sum += ispos ? pos_t : neg_t;
            cnt += ispos ? 1.0f : 0.0f;
        }
    }
    float r0 = block_reduce(sum, sbuf);
    float r1 = block_reduce(cnt, sbuf);
    if (threadIdx.x == 0) {
        ws[WS_FOCAL + idx * 2 + 0] = r0;
        ws[WS_FOCAL + idx * 2 + 1] = r1;
    }
}

__device__ __forceinline__ void wh_part(int blk, const float* __restrict__ o,
                                        const float* __restrict__ tg,
                                        const float* __restrict__ m,
                                        float* __restrict__ ws, float* sbuf) {
    const float4* po  = (const float4*)o;
    const float4* pt  = (const float4*)tg;
    const float4* pmk = (const float4*)m;
    float sl = 0.f, ms = 0.f;
    #pragma unroll 4
    for (int it = 0; it < 32; ++it) {
        int i = blk * 256 + threadIdx.x + it * 16384;
        float4 a = po[i], b = pt[i], c = pmk[i];
        #pragma unroll
        for (int j = 0; j < 4; ++j) {
            float mm = (&c.x)[j];
            float d  = (&a.x)[j] * mm - (&b.x)[j] * mm;
            float ad = fabsf(d);
            sl += (ad < 1.0f) ? 0.5f * d * d : (ad - 0.5f);
            ms += mm;
        }
    }
    float r0 = block_reduce(sl, sbuf);
    float r1 = block_reduce(ms, sbuf);
    if (threadIdx.x == 0) {
        ws[WS_WH + blk * 2 + 0] = r0;
        ws[WS_WH + blk * 2 + 1] = r1;
    }
}

__device__ __forceinline__ void tan_part(int idx, const float* __restrict__ tan_out,
                                         const float* __restrict__ normals,
                                         const int* __restrict__ pts,
                                         float* __restrict__ ws, float* sbuf) {
    int b = idx >> 3, seg = idx & 7;
    float s = 0.f;
    for (int p = seg * 1024 + threadIdx.x; p < seg * 1024 + 1024; p += 256) {
        int base = (b * PP + p) * 2;
        int py = pts[base], px = pts[base + 1];
        int pix = py * WIDTH + px;
        float t0 = tan_out[b * 2 * HW + pix];
        float t1 = tan_out[b * 2 * HW + HW + pix];
        float inv = 1.0f / fmaxf(sqrtf(t0 * t0 + t1 * t1), EPSF);
        float n0 = normals[base], n1 = normals[base + 1];
        s += 1.0f - (n0 * t0 + n1 * t1) * inv;
    }
    float r = block_reduce(s, sbuf);
    if (threadIdx.x == 0) ws[WS_TAN + idx] = r;
}

__device__ __forceinline__ void var_part(int idx, const float* __restrict__ ae,
                                         const int* __restrict__ centers,
                                         const int* __restrict__ kps,
                                         float* __restrict__ ws, float* smem) {
    int n = idx & 31, b = idx >> 5;
    float* cy = smem, *cx = smem + 32, *sbuf = smem + 64;
    if (threadIdx.x < NN) {
        int cb = (b * NN + threadIdx.x) * 2;
        cy[threadIdx.x] = centers[cb]     * (1.0f / 512.0f);
        cx[threadIdx.x] = centers[cb + 1] * (1.0f / 512.0f);
    }
    __syncthreads();
    int k = threadIdx.x;
    int kb = ((b * NN + n) * KK + k) * 2;
    int ky = kps[kb], kx = kps[kb + 1];
    int pix = ky * WIDTH + kx;
    const float* aeb = ae + (size_t)b * 4 * HW;
    float se0 = ftanh(aeb[pix])      + ky * (1.0f / 512.0f);
    float se1 = ftanh(aeb[HW + pix]) + kx * (1.0f / 512.0f);
    float sg0 = __expf(aeb[2 * HW + pix]);
    float sg1 = __expf(aeb[3 * HW + pix]);
    float own = 0.f, mx = -1e30f;
    #pragma unroll
    for (int m = 0; m < NN; ++m) {
        float d0 = se0 - cy[m], d1 = se1 - cx[m];
        float dist = __expf(-(d0 * d0 * sg0 + d1 * d1 * sg1));
        mx = fmaxf(mx, dist);
        if (m == n) own = dist;
    }
    float r = block_reduce(fabsf(own - mx), sbuf);
    if (threadIdx.x == 0) ws[WS_VAR + b * NN + n] = r;
}

// ---- the mega kernel: one dispatch for all partials ----
__global__ void __launch_bounds__(256)
k_mega(const float* __restrict__ cls_out, const float* __restrict__ wh_out,
       const float* __restrict__ kp_out,  const float* __restrict__ ae_out,
       const float* __restrict__ tan_out, const float* __restrict__ cls_mask,
       const float* __restrict__ wh_target, const float* __restrict__ wh_mask,
       const float* __restrict__ kp_mask, const float* __restrict__ ae_masks,
       const float* __restrict__ tan_normals,
       const int* __restrict__ centers, const int* __restrict__ kps,
       const int* __restrict__ tan_points, float* __restrict__ ws) {
    __shared__ float smem[160];
    int bid = blockIdx.x;
    if (bid < NBLK_INST) {
        inst_part(bid, ae_out, ae_masks, centers, ws, smem);
    } else if (bid < NBLK_INST + NBLK_FOCAL) {
        focal_part(bid - NBLK_INST, cls_out, cls_mask, kp_out, kp_mask, ws, smem);
    } else if (bid < NBLK_INST + NBLK_FOCAL + NBLK_WH) {
        wh_part(bid - NBLK_INST - NBLK_FOCAL, wh_out, wh_target, wh_mask, ws, smem);
    } else if (bid < NBLK_INST + NBLK_FOCAL + NBLK_WH + NBLK_TAN) {
        tan_part(bid - NBLK_INST - NBLK_FOCAL - NBLK_WH, tan_out, tan_normals,
                 tan_points, ws, smem);
    } else {
        var_part(bid - NBLK_INST - NBLK_FOCAL - NBLK_WH - NBLK_TAN, ae_out,
                 centers, kps, ws, smem);
    }
}

// ---- finalize: 1 block ----
__global__ void __launch_bounds__(256)
k_final(const float* __restrict__ ws, float* __restrict__ out) {
    __shared__ float sh[256];
    __shared__ float sbuf[4];
    int tid = threadIdx.x;
    float acc = 0.f;
    #pragma unroll 8
    for (int c = 0; c < 64; ++c) acc += ws[WS_INST + c * 256 + tid];
    sh[tid] = acc;
    __syncthreads();
    float ae_v = 0.f;
    if (tid < 128) {   // tid = b*32 + n
        float sum = sh[tid * 2], cnt = sh[tid * 2 + 1];
        // where(np>0, -(pos+neg)/max(np,1), -neg) == -(sum)/max(np,1)  (np==0 => pos==0)
        ae_v = -sum / fmaxf(cnt, 1.0f) + ws[WS_VAR + tid];
    }
    float ae_sum = block_reduce(ae_v, sbuf);

    float fv = ws[WS_FOCAL + tid];
    float cls_sum = block_reduce((tid < 128 && !(tid & 1)) ? fv : 0.f, sbuf);
    float cls_cnt = block_reduce((tid < 128 &&  (tid & 1)) ? fv : 0.f, sbuf);
    float kp_sum  = block_reduce((tid >= 128 && !(tid & 1)) ? fv : 0.f, sbuf);
    float kp_cnt  = block_reduce((tid >= 128 &&  (tid & 1)) ? fv : 0.f, sbuf);

    float wv = (tid < 128) ? ws[WS_WH + tid] : 0.f;
    float wh_sl = block_reduce(!(tid & 1) ? wv : 0.f, sbuf);
    float wh_ms = block_reduce( (tid & 1) ? wv : 0.f, sbuf);

    float tan_sum = block_reduce(tid < 32 ? ws[WS_TAN + tid] : 0.f, sbuf);

    if (tid == 0) {
        float l_cls = -cls_sum / fmaxf(cls_cnt, 1.0f);
        float l_kp  = -kp_sum  / fmaxf(kp_cnt,  1.0f);
        float l_wh  = 0.1f * wh_sl / (wh_ms + 1e-4f);
        float l_ae  = ae_sum / (float)(NN * BB);
        float l_tan = tan_sum / (float)(PP * BB);
        out[0] = l_cls + l_wh + l_kp + l_ae + l_tan;
    }
}

extern "C" void kernel_launch(void* const* d_in, const int* in_sizes, int n_in,
                              void* d_out, int out_size, void* d_ws, size_t ws_size,
                              hipStream_t stream) {
    const float* cls_out     = (const float*)d_in[0];
    const float* wh_out      = (const float*)d_in[1];
    const float* kp_out      = (const float*)d_in[2];
    const float* ae_out      = (const float*)d_in[3];
    const float* tan_out     = (const float*)d_in[4];
    const float* cls_mask    = (const float*)d_in[5];
    const float* wh_target   = (const float*)d_in[6];
    const float* wh_mask     = (const float*)d_in[7];
    const float* kp_mask     = (const float*)d_in[8];
    const float* ae_masks    = (const float*)d_in[9];
    const float* tan_normals = (const float*)d_in[10];
    // d_in[11] = xym: analytic (y/512, x/512)
    const int* centers    = (const int*)d_in[12];
    const int* kps        = (const int*)d_in[13];
    const int* tan_points = (const int*)d_in[14];
    float* ws  = (float*)d_ws;
    float* out = (float*)d_out;

    k_mega<<<NBLK_TOTAL, 256, 0, stream>>>(cls_out, wh_out, kp_out, ae_out, tan_out,
                                           cls_mask, wh_target, wh_mask, kp_mask,
                                           ae_masks, tan_normals, centers, kps,
                                           tan_points, ws);
    k_final<<<1, 256, 0, stream>>>(ws, out);
}